// Round 1
// baseline (6011.486 us; speedup 1.0000x reference)
//
#include <hip/hip_runtime.h>

#define N_NODES   100000
#define N_EDGES   1600000
#define NUM_REL   4
#define NUM_GRAPHS 256

// ---- monotonic float<->uint encoding for atomicMax on floats ----
__device__ __forceinline__ unsigned fenc(float f) {
    unsigned u = __float_as_uint(f);
    return (u & 0x80000000u) ? ~u : (u | 0x80000000u);
}
__device__ __forceinline__ float fdec(unsigned e) {
    return __uint_as_float((e & 0x80000000u) ? (e ^ 0x80000000u) : ~e);
}

// zero the per-(node,rel) edge counts and init the pooling buffer to enc(-inf)
__global__ void init_kernel(float* __restrict__ cnt, unsigned* __restrict__ pool) {
    int i = blockIdx.x * blockDim.x + threadIdx.x;
    if (i < N_NODES * NUM_REL) cnt[i] = 0.0f;
    if (i < NUM_GRAPHS * 64) pool[i] = fenc(-INFINITY);
}

// per-edge scatter: pre_agg[dst,rel,:] += x[src,:]; optionally count edges per (dst,rel)
template<int DIN, bool COUNT>
__global__ void scatter_kernel(const float* __restrict__ x,
                               const int* __restrict__ src,
                               const int* __restrict__ dst,
                               const int* __restrict__ etype,
                               float* __restrict__ pre,
                               float* __restrict__ cnt) {
    int e = blockIdx.x * blockDim.x + threadIdx.x;
    if (e >= N_EDGES) return;
    int s = src[e], d = dst[e], r = etype[e];
    if (COUNT) atomicAdd(cnt + d * NUM_REL + r, 1.0f);
    const float* xs = x + (size_t)s * DIN;
    float* pa = pre + ((size_t)d * NUM_REL + r) * DIN;
#pragma unroll
    for (int i = 0; i < DIN; i += 4) {
        float4 v = *(const float4*)(xs + i);
        atomicAdd(pa + i + 0, v.x);
        atomicAdd(pa + i + 1, v.y);
        atomicAdd(pa + i + 2, v.z);
        atomicAdd(pa + i + 3, v.w);
    }
}

// per-node transform: out = bias + x@root + sum_r (pre_agg[n,r]/max(cnt,1)) @ W[r]
// optional ReLU; optional fused segment_max pooling (layer 3)
template<int DIN, int DOUT, bool RELU, bool POOL>
__global__ void transform_kernel(const float* __restrict__ xin,
                                 const float* __restrict__ pre,
                                 const float* __restrict__ cnt,
                                 const float* __restrict__ W,    // [R, DIN, DOUT]
                                 const float* __restrict__ root, // [DIN, DOUT]
                                 const float* __restrict__ bias, // [DOUT]
                                 float* __restrict__ hout,       // [N, DOUT] (if !POOL)
                                 const int* __restrict__ batch,
                                 unsigned* __restrict__ pool) {
    int n = blockIdx.x * blockDim.x + threadIdx.x;
    if (n >= N_NODES) return;
    float acc[DOUT];
#pragma unroll
    for (int j = 0; j < DOUT; ++j) acc[j] = bias[j];

    // root (self) transform
    const float* xr = xin + (size_t)n * DIN;
#pragma unroll 4
    for (int i = 0; i < DIN; ++i) {
        float xi = xr[i];
#pragma unroll
        for (int j = 0; j < DOUT; ++j) acc[j] = fmaf(xi, root[i * DOUT + j], acc[j]);
    }

    // relation transforms of the mean-aggregated neighborhoods
    for (int r = 0; r < NUM_REL; ++r) {
        float c = cnt[n * NUM_REL + r];
        float inv = 1.0f / fmaxf(c, 1.0f);
        const float* pr = pre + ((size_t)n * NUM_REL + r) * DIN;
        const float* Wr = W + r * DIN * DOUT;
        for (int i = 0; i < DIN; ++i) {
            float v = pr[i] * inv;
#pragma unroll
            for (int j = 0; j < DOUT; ++j) acc[j] = fmaf(v, Wr[i * DOUT + j], acc[j]);
        }
    }

    if (POOL) {
        int g = batch[n];
        unsigned* pg = pool + g * DOUT;
#pragma unroll
        for (int j = 0; j < DOUT; ++j) atomicMax(pg + j, fenc(acc[j]));
    } else {
        float* ho = hout + (size_t)n * DOUT;
#pragma unroll
        for (int j = 0; j < DOUT; ++j) {
            float v = acc[j];
            if (RELU) v = fmaxf(v, 0.0f);
            ho[j] = v;
        }
    }
}

__global__ void decode_kernel(const unsigned* __restrict__ pool, float* __restrict__ out) {
    int i = blockIdx.x * blockDim.x + threadIdx.x;
    if (i < NUM_GRAPHS * 64) out[i] = fdec(pool[i]);
}

extern "C" void kernel_launch(void* const* d_in, const int* in_sizes, int n_in,
                              void* d_out, int out_size, void* d_ws, size_t ws_size,
                              hipStream_t stream) {
    const float* x     = (const float*)d_in[0];
    const int*   ei    = (const int*)d_in[1];
    const int*   etype = (const int*)d_in[2];
    const int*   batch = (const int*)d_in[3];
    const float* W1 = (const float*)d_in[4],  *root1 = (const float*)d_in[5],  *b1 = (const float*)d_in[6];
    const float* W2 = (const float*)d_in[7],  *root2 = (const float*)d_in[8],  *b2 = (const float*)d_in[9];
    const float* W3 = (const float*)d_in[10], *root3 = (const float*)d_in[11], *b3 = (const float*)d_in[12];
    float* out = (float*)d_out;

    const int* src = ei;
    const int* dst = ei + N_EDGES;

    // workspace layout (floats)
    float*    cnt  = (float*)d_ws;                                   // N*R
    float*    pre  = cnt + (size_t)N_NODES * NUM_REL;                // N*R*32 (max DIN)
    float*    h1   = pre + (size_t)N_NODES * NUM_REL * 32;           // N*16
    float*    h2   = h1 + (size_t)N_NODES * 16;                      // N*32
    unsigned* pool = (unsigned*)(h2 + (size_t)N_NODES * 32);         // 256*64

    const int BT = 256;
    const int gE = (N_EDGES + BT - 1) / BT;
    const int gN = (N_NODES + BT - 1) / BT;
    const int gI = (N_NODES * NUM_REL + BT - 1) / BT;

    init_kernel<<<gI, BT, 0, stream>>>(cnt, pool);

    // ---- layer 1: 16 -> 16, relu ----
    hipMemsetAsync(pre, 0, (size_t)N_NODES * NUM_REL * 16 * sizeof(float), stream);
    scatter_kernel<16, true><<<gE, BT, 0, stream>>>(x, src, dst, etype, pre, cnt);
    transform_kernel<16, 16, true, false><<<gN, BT, 0, stream>>>(
        x, pre, cnt, W1, root1, b1, h1, batch, pool);

    // ---- layer 2: 16 -> 32, relu ----
    hipMemsetAsync(pre, 0, (size_t)N_NODES * NUM_REL * 16 * sizeof(float), stream);
    scatter_kernel<16, false><<<gE, BT, 0, stream>>>(h1, src, dst, etype, pre, cnt);
    transform_kernel<16, 32, true, false><<<gN, BT, 0, stream>>>(
        h1, pre, cnt, W2, root2, b2, h2, batch, pool);

    // ---- layer 3: 32 -> 64, no relu, fused max-pool ----
    hipMemsetAsync(pre, 0, (size_t)N_NODES * NUM_REL * 32 * sizeof(float), stream);
    scatter_kernel<32, false><<<gE, BT, 0, stream>>>(h2, src, dst, etype, pre, cnt);
    transform_kernel<32, 64, false, true><<<gN, BT, 0, stream>>>(
        h2, pre, cnt, W3, root3, b3, nullptr, batch, pool);

    decode_kernel<<<(NUM_GRAPHS * 64 + BT - 1) / BT, BT, 0, stream>>>(pool, out);
}

// Round 3
// 603.840 us; speedup vs baseline: 9.9554x; 9.9554x over previous
//
#include <hip/hip_runtime.h>

#define N_NODES    100000
#define N_EDGES    1600000
#define NUM_REL    4
#define NUM_GRAPHS 256

constexpr int NR       = N_NODES * NUM_REL;   // 400000 segments
constexpr int NB       = (NR + 255) / 256;    // 1563 scan blocks
constexpr int SB_ITEMS = (NB + 255) / 256;    // 7 items/thread in scanB

// ---- monotonic float<->uint encoding for atomicMax on floats ----
__device__ __forceinline__ unsigned fenc(float f) {
    unsigned u = __float_as_uint(f);
    return (u & 0x80000000u) ? ~u : (u | 0x80000000u);
}
__device__ __forceinline__ float fdec(unsigned e) {
    return __uint_as_float((e & 0x80000000u) ? (e ^ 0x80000000u) : ~e);
}

__global__ void init_kernel(int* __restrict__ cnt, unsigned* __restrict__ pool) {
    int i = blockIdx.x * blockDim.x + threadIdx.x;
    if (i < NR) cnt[i] = 0;
    if (i < NUM_GRAPHS * 64) pool[i] = fenc(-INFINITY);
}

// count edges per (dst, rel) segment
__global__ void count_kernel(const int* __restrict__ dst, const int* __restrict__ etype,
                             int* __restrict__ cnt) {
    int e = blockIdx.x * 256 + threadIdx.x;
    if (e >= N_EDGES) return;
    atomicAdd(cnt + dst[e] * NUM_REL + etype[e], 1);
}

// per-block inclusive scan of cnt -> incl; block totals -> bsums
__global__ void scanA_kernel(const int* __restrict__ cnt, int* __restrict__ incl,
                             int* __restrict__ bsums) {
    __shared__ int sd[256];
    int t = threadIdx.x;
    int idx = blockIdx.x * 256 + t;
    sd[t] = (idx < NR) ? cnt[idx] : 0;
    __syncthreads();
#pragma unroll
    for (int off = 1; off < 256; off <<= 1) {
        int a = (t >= off) ? sd[t - off] : 0;
        __syncthreads();
        sd[t] += a;
        __syncthreads();
    }
    if (idx < NR) incl[idx] = sd[t];
    if (t == 255) bsums[blockIdx.x] = sd[255];
}

// single-block exclusive scan of the block sums
__global__ void scanB_kernel(const int* __restrict__ bsums, int* __restrict__ boffs) {
    __shared__ int sd[256];
    int t = threadIdx.x;
    int pre[SB_ITEMS];
    int run = 0;
#pragma unroll
    for (int k = 0; k < SB_ITEMS; ++k) {
        int ix = t * SB_ITEMS + k;
        pre[k] = run;
        run += (ix < NB) ? bsums[ix] : 0;
    }
    sd[t] = run;
    __syncthreads();
#pragma unroll
    for (int off = 1; off < 256; off <<= 1) {
        int a = (t >= off) ? sd[t - off] : 0;
        __syncthreads();
        sd[t] += a;
        __syncthreads();
    }
    int excl = sd[t] - run;
#pragma unroll
    for (int k = 0; k < SB_ITEMS; ++k) {
        int ix = t * SB_ITEMS + k;
        if (ix < NB) boffs[ix] = excl + pre[k];
    }
}

// finalize exclusive offsets (in place over incl) and init cursor copy
__global__ void scanC_kernel(const int* __restrict__ cnt, int* __restrict__ offs_inout,
                             const int* __restrict__ boffs, int* __restrict__ cursor) {
    int idx = blockIdx.x * 256 + threadIdx.x;
    if (idx >= NR) return;
    int e = boffs[idx >> 8] + offs_inout[idx] - cnt[idx];
    offs_inout[idx] = e;
    cursor[idx] = e;
}

// place src node ids into CSR slots
__global__ void place_kernel(const int* __restrict__ src, const int* __restrict__ dst,
                             const int* __restrict__ etype, int* __restrict__ cursor,
                             int* __restrict__ csr) {
    int e = blockIdx.x * 256 + threadIdx.x;
    if (e >= N_EDGES) return;
    int seg = dst[e] * NUM_REL + etype[e];
    int pos = atomicAdd(cursor + seg, 1);
    csr[pos] = src[e];
}

// fused per-node: gather per-relation means (CSR) -> LDS, then transform
// out = bias + x@root + sum_r mean_r @ W_r ; optional ReLU ; optional fused max-pool
template<int DIN, int DOUT, bool RELU, bool POOL>
__global__ __launch_bounds__(256)
void layer_kernel(const float* __restrict__ x,
                  const int* __restrict__ csr,
                  const int* __restrict__ offsets,
                  const int* __restrict__ cnt,
                  const float* __restrict__ W,     // [R, DIN, DOUT]
                  const float* __restrict__ root,  // [DIN, DOUT]
                  const float* __restrict__ bias,  // [DOUT]
                  float* __restrict__ hout,        // [N, DOUT] if !POOL
                  const int* __restrict__ batch,
                  unsigned* __restrict__ pool) {
    __shared__ float mean[4][NUM_REL][DIN];
    __shared__ float xrow[4][DIN];
    __shared__ float pval[4][64];
    __shared__ int   pg[4];
    __shared__ int   sameflag;

    const int w    = threadIdx.x >> 6;
    const int lane = threadIdx.x & 63;
    const int n    = blockIdx.x * 4 + w;   // 100000 = 4 * 25000, exact

    // ---- aggregation (gather) ----
    if constexpr (DIN == 16) {
        int r = lane >> 4, i = lane & 15;
        int seg = n * NUM_REL + r;
        int start = offsets[seg], len = cnt[seg];
        float s = 0.f;
        for (int k = 0; k < len; ++k)
            s += x[(size_t)csr[start + k] * DIN + i];
        mean[w][r][i] = s * (1.0f / fmaxf((float)len, 1.0f));
        if (r == 0) xrow[w][i] = x[(size_t)n * DIN + i];
    } else { // DIN == 32
        int r2 = lane >> 5, i = lane & 31;
#pragma unroll
        for (int pass = 0; pass < 2; ++pass) {
            int r = pass * 2 + r2;
            int seg = n * NUM_REL + r;
            int start = offsets[seg], len = cnt[seg];
            float s = 0.f;
            for (int k = 0; k < len; ++k)
                s += x[(size_t)csr[start + k] * DIN + i];
            mean[w][r][i] = s * (1.0f / fmaxf((float)len, 1.0f));
        }
        if (lane < 32) xrow[w][lane] = x[(size_t)n * DIN + lane];
    }
    __syncthreads();

    // ---- transform ----
    constexpr int Q = 64 / DOUT;      // 4, 2, 1
    const int j = lane % DOUT;
    const int q = lane / DOUT;
    float acc = 0.f;
    for (int t = q; t < NUM_REL + 1; t += Q) {
        if (t == 0) {
#pragma unroll
            for (int i = 0; i < DIN; ++i)
                acc = fmaf(xrow[w][i], root[i * DOUT + j], acc);
        } else {
            const int r = t - 1;
            const float* Wr = W + r * DIN * DOUT;
            const float* m = mean[w][r];
#pragma unroll
            for (int i = 0; i < DIN; ++i)
                acc = fmaf(m[i], Wr[i * DOUT + j], acc);
        }
    }
#pragma unroll
    for (int off = DOUT; off < 64; off <<= 1)
        acc += __shfl_xor(acc, off, 64);
    acc += bias[j];

    if constexpr (POOL) {
        // DOUT == 64: every lane holds channel j = lane
        pval[w][lane] = acc;
        if (lane == 0) pg[w] = batch[n];
        __syncthreads();
        if (threadIdx.x == 0)
            sameflag = (pg[0] == pg[1]) && (pg[0] == pg[2]) && (pg[0] == pg[3]);
        __syncthreads();
        if (sameflag) {
            if (w == 0) {
                float m0 = fmaxf(fmaxf(pval[0][lane], pval[1][lane]),
                                 fmaxf(pval[2][lane], pval[3][lane]));
                atomicMax(pool + pg[0] * 64 + lane, fenc(m0));
            }
        } else {
            atomicMax(pool + pg[w] * 64 + lane, fenc(pval[w][lane]));
        }
    } else {
        if (lane < DOUT) {
            float v = RELU ? fmaxf(acc, 0.f) : acc;
            hout[(size_t)n * DOUT + j] = v;
        }
    }
}

__global__ void decode_kernel(const unsigned* __restrict__ pool, float* __restrict__ out) {
    int i = blockIdx.x * blockDim.x + threadIdx.x;
    if (i < NUM_GRAPHS * 64) out[i] = fdec(pool[i]);
}

extern "C" void kernel_launch(void* const* d_in, const int* in_sizes, int n_in,
                              void* d_out, int out_size, void* d_ws, size_t ws_size,
                              hipStream_t stream) {
    const float* x     = (const float*)d_in[0];
    const int*   ei    = (const int*)d_in[1];
    const int*   etype = (const int*)d_in[2];
    const int*   batch = (const int*)d_in[3];
    const float* W1 = (const float*)d_in[4],  *root1 = (const float*)d_in[5],  *b1 = (const float*)d_in[6];
    const float* W2 = (const float*)d_in[7],  *root2 = (const float*)d_in[8],  *b2 = (const float*)d_in[9];
    const float* W3 = (const float*)d_in[10], *root3 = (const float*)d_in[11], *b3 = (const float*)d_in[12];
    float* out = (float*)d_out;

    const int* src = ei;
    const int* dst = ei + N_EDGES;

    // workspace layout (ints/floats), ~30.5 MB total
    int*      cnt    = (int*)d_ws;                 // NR
    int*      offs   = cnt + NR;                   // NR (incl-scan then exclusive offsets)
    int*      cursor = offs + NR;                  // NR
    int*      bsums  = cursor + NR;                // 2048
    int*      boffs  = bsums + 2048;               // 2048
    int*      csr    = boffs + 2048;               // N_EDGES
    float*    h1     = (float*)(csr + N_EDGES);    // N*16
    float*    h2     = h1 + (size_t)N_NODES * 16;  // N*32
    unsigned* pool   = (unsigned*)(h2 + (size_t)N_NODES * 32); // 256*64

    const int BT = 256;
    const int gE = (N_EDGES + BT - 1) / BT;
    const int gI = (NR + BT - 1) / BT;
    const int gL = N_NODES / 4;

    init_kernel<<<gI, BT, 0, stream>>>(cnt, pool);
    count_kernel<<<gE, BT, 0, stream>>>(dst, etype, cnt);
    scanA_kernel<<<NB, BT, 0, stream>>>(cnt, offs, bsums);
    scanB_kernel<<<1, BT, 0, stream>>>(bsums, boffs);
    scanC_kernel<<<gI, BT, 0, stream>>>(cnt, offs, boffs, cursor);
    place_kernel<<<gE, BT, 0, stream>>>(src, dst, etype, cursor, csr);

    layer_kernel<16, 16, true,  false><<<gL, BT, 0, stream>>>(
        x,  csr, offs, cnt, W1, root1, b1, h1, batch, pool);
    layer_kernel<16, 32, true,  false><<<gL, BT, 0, stream>>>(
        h1, csr, offs, cnt, W2, root2, b2, h2, batch, pool);
    layer_kernel<32, 64, false, true ><<<gL, BT, 0, stream>>>(
        h2, csr, offs, cnt, W3, root3, b3, nullptr, batch, pool);

    decode_kernel<<<(NUM_GRAPHS * 64 + BT - 1) / BT, BT, 0, stream>>>(pool, out);
}

// Round 4
// 482.417 us; speedup vs baseline: 12.4612x; 1.2517x over previous
//
#include <hip/hip_runtime.h>

#define N_NODES    100000
#define N_EDGES    1600000
#define NUM_REL    4
#define NUM_GRAPHS 256

constexpr int NR       = N_NODES * NUM_REL;   // 400000 segments
constexpr int NB       = (NR + 255) / 256;    // 1563 scan blocks
constexpr int SB_ITEMS = (NB + 255) / 256;    // 7 items/thread in scanB

// ---- monotonic float<->uint encoding for atomicMax on floats ----
__device__ __forceinline__ unsigned fenc(float f) {
    unsigned u = __float_as_uint(f);
    return (u & 0x80000000u) ? ~u : (u | 0x80000000u);
}
__device__ __forceinline__ float fdec(unsigned e) {
    return __uint_as_float((e & 0x80000000u) ? (e ^ 0x80000000u) : ~e);
}

__global__ void init_kernel(int* __restrict__ cnt, unsigned* __restrict__ pool) {
    int i = blockIdx.x * blockDim.x + threadIdx.x;
    if (i < NR) cnt[i] = 0;
    if (i < NUM_GRAPHS * 64) pool[i] = fenc(-INFINITY);
}

// count edges per (dst, rel) segment
__global__ void count_kernel(const int* __restrict__ dst, const int* __restrict__ etype,
                             int* __restrict__ cnt) {
    int e = blockIdx.x * 256 + threadIdx.x;
    if (e >= N_EDGES) return;
    atomicAdd(cnt + dst[e] * NUM_REL + etype[e], 1);
}

// per-block inclusive scan of cnt -> incl; block totals -> bsums
__global__ void scanA_kernel(const int* __restrict__ cnt, int* __restrict__ incl,
                             int* __restrict__ bsums) {
    __shared__ int sd[256];
    int t = threadIdx.x;
    int idx = blockIdx.x * 256 + t;
    sd[t] = (idx < NR) ? cnt[idx] : 0;
    __syncthreads();
#pragma unroll
    for (int off = 1; off < 256; off <<= 1) {
        int a = (t >= off) ? sd[t - off] : 0;
        __syncthreads();
        sd[t] += a;
        __syncthreads();
    }
    if (idx < NR) incl[idx] = sd[t];
    if (t == 255) bsums[blockIdx.x] = sd[255];
}

// single-block exclusive scan of the block sums
__global__ void scanB_kernel(const int* __restrict__ bsums, int* __restrict__ boffs) {
    __shared__ int sd[256];
    int t = threadIdx.x;
    int pre[SB_ITEMS];
    int run = 0;
#pragma unroll
    for (int k = 0; k < SB_ITEMS; ++k) {
        int ix = t * SB_ITEMS + k;
        pre[k] = run;
        run += (ix < NB) ? bsums[ix] : 0;
    }
    sd[t] = run;
    __syncthreads();
#pragma unroll
    for (int off = 1; off < 256; off <<= 1) {
        int a = (t >= off) ? sd[t - off] : 0;
        __syncthreads();
        sd[t] += a;
        __syncthreads();
    }
    int excl = sd[t] - run;
#pragma unroll
    for (int k = 0; k < SB_ITEMS; ++k) {
        int ix = t * SB_ITEMS + k;
        if (ix < NB) boffs[ix] = excl + pre[k];
    }
}

// finalize exclusive offsets in place over incl (no separate cursor array)
__global__ void scanC_kernel(const int* __restrict__ cnt, int* __restrict__ offs_inout,
                             const int* __restrict__ boffs) {
    int idx = blockIdx.x * 256 + threadIdx.x;
    if (idx >= NR) return;
    offs_inout[idx] = boffs[idx >> 8] + offs_inout[idx] - cnt[idx];
}

// place src node ids into CSR slots; offs[seg] ends at segment END (= start + cnt)
__global__ void place_kernel(const int* __restrict__ src, const int* __restrict__ dst,
                             const int* __restrict__ etype, int* __restrict__ offs,
                             int* __restrict__ csr) {
    int e = blockIdx.x * 256 + threadIdx.x;
    if (e >= N_EDGES) return;
    int seg = dst[e] * NUM_REL + etype[e];
    int pos = atomicAdd(offs + seg, 1);
    csr[pos] = src[e];
}

// 8-way ILP gather of one segment: sum of x[csr[start..start+len)][i]
template<int DIN>
__device__ __forceinline__ float gather_sum(const float* __restrict__ x,
                                            const int* __restrict__ csr,
                                            int start, int len, int i) {
    float s0 = 0.f, s1 = 0.f, s2 = 0.f, s3 = 0.f;
    float s4 = 0.f, s5 = 0.f, s6 = 0.f, s7 = 0.f;
    for (int k = 0; k < len; k += 8) {
        int lim = len - k;                      // >=1
        int c[8];
#pragma unroll
        for (int m = 0; m < 8; ++m)
            c[m] = csr[start + (m < lim ? k + m : k)];
        float v[8];
#pragma unroll
        for (int m = 0; m < 8; ++m)
            v[m] = x[(size_t)c[m] * DIN + i];
        if (0 < lim) s0 += v[0];
        if (1 < lim) s1 += v[1];
        if (2 < lim) s2 += v[2];
        if (3 < lim) s3 += v[3];
        if (4 < lim) s4 += v[4];
        if (5 < lim) s5 += v[5];
        if (6 < lim) s6 += v[6];
        if (7 < lim) s7 += v[7];
    }
    return ((s0 + s1) + (s2 + s3)) + ((s4 + s5) + (s6 + s7));
}

// fused per-node: gather per-relation means (CSR) -> LDS, then transform
// out = bias + x@root + sum_r mean_r @ W_r ; optional ReLU ; optional fused max-pool
// NOTE: offsets[] holds segment END (start = offsets[seg] - cnt[seg]) after place_kernel.
template<int DIN, int DOUT, bool RELU, bool POOL>
__global__ __launch_bounds__(256)
void layer_kernel(const float* __restrict__ x,
                  const int* __restrict__ csr,
                  const int* __restrict__ offsets,
                  const int* __restrict__ cnt,
                  const float* __restrict__ W,     // [R, DIN, DOUT]
                  const float* __restrict__ root,  // [DIN, DOUT]
                  const float* __restrict__ bias,  // [DOUT]
                  float* __restrict__ hout,        // [N, DOUT] if !POOL
                  const int* __restrict__ batch,
                  unsigned* __restrict__ pool) {
    __shared__ float mean[4][NUM_REL][DIN];
    __shared__ float xrow[4][DIN];
    __shared__ float pval[4][64];
    __shared__ int   pg[4];
    __shared__ int   sameflag;

    const int w    = threadIdx.x >> 6;
    const int lane = threadIdx.x & 63;
    const int n    = blockIdx.x * 4 + w;   // 100000 = 4 * 25000, exact

    // ---- aggregation (gather, 8-way ILP) ----
    if constexpr (DIN == 16) {
        int r = lane >> 4, i = lane & 15;
        int seg = n * NUM_REL + r;
        int len = cnt[seg];
        int start = offsets[seg] - len;
        float s = (len > 0) ? gather_sum<16>(x, csr, start, len, i) : 0.f;
        mean[w][r][i] = s * (1.0f / fmaxf((float)len, 1.0f));
        if (r == 0) xrow[w][i] = x[(size_t)n * DIN + i];
    } else { // DIN == 32
        int r2 = lane >> 5, i = lane & 31;
#pragma unroll
        for (int pass = 0; pass < 2; ++pass) {
            int r = pass * 2 + r2;
            int seg = n * NUM_REL + r;
            int len = cnt[seg];
            int start = offsets[seg] - len;
            float s = (len > 0) ? gather_sum<32>(x, csr, start, len, i) : 0.f;
            mean[w][r][i] = s * (1.0f / fmaxf((float)len, 1.0f));
        }
        if (lane < 32) xrow[w][lane] = x[(size_t)n * DIN + lane];
    }
    __syncthreads();

    // ---- transform ----
    constexpr int Q = 64 / DOUT;      // 4, 2, 1
    const int j = lane % DOUT;
    const int q = lane / DOUT;
    float acc = 0.f;
    for (int t = q; t < NUM_REL + 1; t += Q) {
        if (t == 0) {
#pragma unroll
            for (int i = 0; i < DIN; ++i)
                acc = fmaf(xrow[w][i], root[i * DOUT + j], acc);
        } else {
            const int r = t - 1;
            const float* Wr = W + r * DIN * DOUT;
            const float* m = mean[w][r];
#pragma unroll
            for (int i = 0; i < DIN; ++i)
                acc = fmaf(m[i], Wr[i * DOUT + j], acc);
        }
    }
#pragma unroll
    for (int off = DOUT; off < 64; off <<= 1)
        acc += __shfl_xor(acc, off, 64);
    acc += bias[j];

    if constexpr (POOL) {
        // DOUT == 64: every lane holds channel j = lane
        pval[w][lane] = acc;
        if (lane == 0) pg[w] = batch[n];
        __syncthreads();
        if (threadIdx.x == 0)
            sameflag = (pg[0] == pg[1]) && (pg[0] == pg[2]) && (pg[0] == pg[3]);
        __syncthreads();
        if (sameflag) {
            if (w == 0) {
                float m0 = fmaxf(fmaxf(pval[0][lane], pval[1][lane]),
                                 fmaxf(pval[2][lane], pval[3][lane]));
                atomicMax(pool + pg[0] * 64 + lane, fenc(m0));
            }
        } else {
            atomicMax(pool + pg[w] * 64 + lane, fenc(pval[w][lane]));
        }
    } else {
        if (lane < DOUT) {
            float v = RELU ? fmaxf(acc, 0.f) : acc;
            hout[(size_t)n * DOUT + j] = v;
        }
    }
}

__global__ void decode_kernel(const unsigned* __restrict__ pool, float* __restrict__ out) {
    int i = blockIdx.x * blockDim.x + threadIdx.x;
    if (i < NUM_GRAPHS * 64) out[i] = fdec(pool[i]);
}

extern "C" void kernel_launch(void* const* d_in, const int* in_sizes, int n_in,
                              void* d_out, int out_size, void* d_ws, size_t ws_size,
                              hipStream_t stream) {
    const float* x     = (const float*)d_in[0];
    const int*   ei    = (const int*)d_in[1];
    const int*   etype = (const int*)d_in[2];
    const int*   batch = (const int*)d_in[3];
    const float* W1 = (const float*)d_in[4],  *root1 = (const float*)d_in[5],  *b1 = (const float*)d_in[6];
    const float* W2 = (const float*)d_in[7],  *root2 = (const float*)d_in[8],  *b2 = (const float*)d_in[9];
    const float* W3 = (const float*)d_in[10], *root3 = (const float*)d_in[11], *b3 = (const float*)d_in[12];
    float* out = (float*)d_out;

    const int* src = ei;
    const int* dst = ei + N_EDGES;

    // workspace layout (ints/floats), ~29 MB total
    int*      cnt    = (int*)d_ws;                 // NR
    int*      offs   = cnt + NR;                   // NR (incl-scan -> excl offsets -> segment ENDs)
    int*      bsums  = offs + NR;                  // 2048
    int*      boffs  = bsums + 2048;               // 2048
    int*      csr    = boffs + 2048;               // N_EDGES
    float*    h1     = (float*)(csr + N_EDGES);    // N*16
    float*    h2     = h1 + (size_t)N_NODES * 16;  // N*32
    unsigned* pool   = (unsigned*)(h2 + (size_t)N_NODES * 32); // 256*64

    const int BT = 256;
    const int gE = (N_EDGES + BT - 1) / BT;
    const int gI = (NR + BT - 1) / BT;
    const int gL = N_NODES / 4;

    init_kernel<<<gI, BT, 0, stream>>>(cnt, pool);
    count_kernel<<<gE, BT, 0, stream>>>(dst, etype, cnt);
    scanA_kernel<<<NB, BT, 0, stream>>>(cnt, offs, bsums);
    scanB_kernel<<<1, BT, 0, stream>>>(bsums, boffs);
    scanC_kernel<<<gI, BT, 0, stream>>>(cnt, offs, boffs);
    place_kernel<<<gE, BT, 0, stream>>>(src, dst, etype, offs, csr);

    layer_kernel<16, 16, true,  false><<<gL, BT, 0, stream>>>(
        x,  csr, offs, cnt, W1, root1, b1, h1, batch, pool);
    layer_kernel<16, 32, true,  false><<<gL, BT, 0, stream>>>(
        h1, csr, offs, cnt, W2, root2, b2, h2, batch, pool);
    layer_kernel<32, 64, false, true ><<<gL, BT, 0, stream>>>(
        h2, csr, offs, cnt, W3, root3, b3, nullptr, batch, pool);

    decode_kernel<<<(NUM_GRAPHS * 64 + BT - 1) / BT, BT, 0, stream>>>(pool, out);
}